// Round 10
// baseline (31.845 us; speedup 1.0000x reference)
//
#include <hip/hip_runtime.h>
#include <math.h>

constexpr int N_RAYS = 65536;
constexpr int NBLK   = 2048;   // 2048 blocks * 4 waves * 2 batches * 4 rays = 65536

// DPP helper: lanes with a valid source get dpp(src); invalid lanes keep `oldv`.
// (row = 16 lanes; row_shr:n = lane i reads lane i-n; row_shl:n = lane i reads i+n)
template<int CTRL>
__device__ __forceinline__ float dppf(float oldv, float x) {
    return __int_as_float(__builtin_amdgcn_update_dpp(
        __float_as_int(oldv), __float_as_int(x), CTRL, 0xF, 0xF, false));
}

__device__ __forceinline__ float row16_sum(float x) {
    x += dppf<0xB1>(0.0f, x);    // quad_perm(1,0,3,2)
    x += dppf<0x4E>(0.0f, x);    // quad_perm(2,3,0,1)
    x += dppf<0x141>(0.0f, x);   // row_half_mirror
    x += dppf<0x140>(0.0f, x);   // row_mirror
    return x;
}

// One wave = 2 pipelined batches of 4 rays (16 lanes/ray = one DPP row).
// Lane m owns samples 8m..8m+7 of its ray. Loads for BOTH batches issue
// up front; batch-0 compute waits only on batch-0 regs (vmcnt>0), so
// batch-1's memory latency hides under batch-0 compute.
__global__ __launch_bounds__(256, 4) void integrate_kernel(
    const float* __restrict__ raw,     // [N][128][4]
    const float* __restrict__ zvals,   // [N][128]
    const float* __restrict__ rays_d,  // [N][3]
    float* __restrict__ chs_map,       // [N][3]
    float* __restrict__ depth_map,     // [N]
    float* __restrict__ block_partials)
{
    const int lane = threadIdx.x & 63;
    const int warp = threadIdx.x >> 6;
    const int g    = lane >> 4;
    const int m    = lane & 15;

    const int wbase = (blockIdx.x * 4 + warp) * 2;   // batch index base
    const int ray0  = (wbase + 0) * 4 + g;
    const int ray1  = (wbase + 1) * 4 + g;

    // ---- issue ALL loads for both batches up front ----
    const float* rd0 = rays_d + ray0 * 3;
    const float* rd1 = rays_d + ray1 * 3;
    const float a00 = rd0[0], a01 = rd0[1], a02 = rd0[2];
    const float a10 = rd1[0], a11 = rd1[1], a12 = rd1[2];

    const float* zr0 = zvals + (ray0 << 7);
    const float* zr1 = zvals + (ray1 << 7);
    const float4 zA0 = *(const float4*)(zr0 + 8 * m);
    const float4 zB0 = *(const float4*)(zr0 + 8 * m + 4);
    const float4 zA1 = *(const float4*)(zr1 + 8 * m);
    const float4 zB1 = *(const float4*)(zr1 + 8 * m + 4);

    const float4* rq0 = (const float4*)raw + (ray0 << 7);
    const float4* rq1 = (const float4*)raw + (ray1 << 7);
    float4 q0[8], q1[8];
    #pragma unroll
    for (int j = 0; j < 8; ++j) q0[j] = rq0[8 * m + j];
    #pragma unroll
    for (int j = 0; j < 8; ++j) q1[j] = rq1[8 * m + j];

    const float norm0 = sqrtf(a00*a00 + a01*a01 + a02*a02);
    const float norm1 = sqrtf(a10*a10 + a11*a11 + a12*a12);

    float ent = 0.0f;

    #pragma unroll
    for (int b = 0; b < 2; ++b) {
        const int   ray  = (b == 0) ? ray0  : ray1;
        const float norm = (b == 0) ? norm0 : norm1;
        const float4 zA  = (b == 0) ? zA0 : zA1;
        const float4 zB  = (b == 0) ? zB0 : zB1;
        float4 q[8];
        #pragma unroll
        for (int j = 0; j < 8; ++j) q[j] = (b == 0) ? q0[j] : q1[j];

        float z[8] = {zA.x, zA.y, zA.z, zA.w, zB.x, zB.y, zB.z, zB.w};
        // lane m+1's z[8m+8] (row-lane 15 invalid -> keeps own z[0], unused)
        const float zn = dppf<0x101>(z[0], z[0]);

        // survival t_j = exp(-relu(sigma)*dist) + 1e-10
        float tt[8];
        #pragma unroll
        for (int j = 0; j < 7; ++j)
            tt[j] = __expf(-fmaxf(q[j].w, 0.0f) * (z[j+1] - z[j]) * norm) + 1e-10f;
        {
            const float dd7 = (m == 15) ? 1e10f : (zn - z[7]);
            tt[7] = __expf(-fmaxf(q[7].w, 0.0f) * dd7 * norm) + 1e-10f;
        }

        // lane-local product, 16-lane inclusive scan, exclusive shift
        float p = tt[0];
        #pragma unroll
        for (int j = 1; j < 8; ++j) p *= tt[j];
        float sc = p;
        sc *= dppf<0x111>(1.0f, sc);   // row_shr:1
        sc *= dppf<0x112>(1.0f, sc);   // row_shr:2
        sc *= dppf<0x114>(1.0f, sc);   // row_shr:4
        sc *= dppf<0x118>(1.0f, sc);   // row_shr:8
        float trj = dppf<0x111>(1.0f, sc);   // exclusive: row-lane0 -> 1

        // weights: w_j = trj_j - trj_{j+1}
        float c0=0.f, c1=0.f, c2=0.f, wsum=0.f, wz=0.f, aa2=0.f;
        #pragma unroll
        for (int j = 0; j < 8; ++j) {
            const float trjn = trj * tt[j];
            const float w    = trj - trjn;
            c0   += w * q[j].x;
            c1   += w * q[j].y;
            c2   += w * q[j].z;
            wsum += w;
            wz   += w * z[j];
            aa2  += w * __log2f(fmaxf(w, 1e-30f));   // log2 domain
            trj   = trjn;
        }

        // 6-var allreduce within the 16-lane row (pure DPP)
        c0   = row16_sum(c0);
        c1   = row16_sum(c1);
        c2   = row16_sum(c2);
        wsum = row16_sum(wsum);
        wz   = row16_sum(wz);
        aa2  = row16_sum(aa2);

        if (m == 0) {
            chs_map[ray * 3 + 0] = c0;
            chs_map[ray * 3 + 1] = c1;
            chs_map[ray * 3 + 2] = c2;
            const float dnum = (6.0f * wsum - wz) * 0.25f;
            depth_map[ray] = dnum / (wsum + 1e-5f);

            // sum p*log p = (A - W*log(psum) + L*(log L - log psum)) / psum
            const float aa = aa2 * 0.6931471806f;
            const float L = 1.0f - wsum + 1e-6f;
            const float psum = wsum + L;
            const float logpsum = __logf(psum);
            const float entL = (L > 0.0f) ? L * (__logf(L) - logpsum) : 0.0f;
            ent -= (aa - wsum * logpsum + entL) / psum;
        }
    }

    // entropy partials on lanes 0,16,32,48 -> lane 0
    ent += __shfl_xor(ent, 16);
    ent += __shfl_xor(ent, 32);

    __shared__ float sred[4];
    if (lane == 0) sred[warp] = ent;
    __syncthreads();
    if (threadIdx.x == 0)
        block_partials[blockIdx.x] = sred[0] + sred[1] + sred[2] + sred[3];
}

__global__ __launch_bounds__(1024) void reduce_kernel(
    const float* __restrict__ partials, float* __restrict__ out_scalar)
{
    float s = 0.0f;
    #pragma unroll
    for (int i = 0; i < NBLK / 1024; ++i)
        s += partials[threadIdx.x + i * 1024];
    #pragma unroll
    for (int d = 1; d < 64; d <<= 1) s += __shfl_xor(s, d);

    __shared__ float sr[16];
    const int lane = threadIdx.x & 63;
    const int warp = threadIdx.x >> 6;
    if (lane == 0) sr[warp] = s;
    __syncthreads();
    if (threadIdx.x == 0) {
        float tot = 0.0f;
        #pragma unroll
        for (int i = 0; i < 16; ++i) tot += sr[i];
        *out_scalar = tot;
    }
}

extern "C" void kernel_launch(void* const* d_in, const int* in_sizes, int n_in,
                              void* d_out, int out_size, void* d_ws, size_t ws_size,
                              hipStream_t stream) {
    const float* raw    = (const float*)d_in[0];
    const float* zvals  = (const float*)d_in[1];
    const float* rays_d = (const float*)d_in[2];

    float* out = (float*)d_out;
    float* chs_map   = out;                       // 65536*3
    float* depth_map = out + (size_t)N_RAYS * 3;  // 65536
    float* sparsity  = out + (size_t)N_RAYS * 4;  // 1

    float* partials = (float*)d_ws;               // NBLK floats

    integrate_kernel<<<NBLK, 256, 0, stream>>>(raw, zvals, rays_d,
                                               chs_map, depth_map, partials);
    reduce_kernel<<<1, 1024, 0, stream>>>(partials, sparsity);
}